// Round 3
// baseline (2875.639 us; speedup 1.0000x reference)
//
#include <hip/hip_runtime.h>

#define N_NODES 100000
#define N_EDGES 1600000
#define HID 64
#define EDIM 32
#define BN_EPS 1e-5f

#define SCAN_CHUNK 1024
#define NB_SCAN ((N_NODES + SCAN_CHUNK - 1) / SCAN_CHUNK)   // 98

// ---------------------------------------------------------------------------
// Counting sort of edges by dst.  Built once per call, reused by all 3 layers.
// ---------------------------------------------------------------------------
__global__ __launch_bounds__(256) void hist_kernel(
    const int* __restrict__ dst, int* __restrict__ cnt)
{
    int i = (int)(blockIdx.x * blockDim.x + threadIdx.x);
    const int stride = (int)(gridDim.x * blockDim.x);
    for (; i < N_EDGES; i += stride) atomicAdd(&cnt[dst[i]], 1);
}

__global__ __launch_bounds__(256) void scan1_kernel(
    const int* __restrict__ cnt, int* __restrict__ bsum)
{
    __shared__ int s[256];
    const int b = (int)blockIdx.x, t = (int)threadIdx.x;
    const int base = b * SCAN_CHUNK + t * 4;
    int sum = 0;
#pragma unroll
    for (int k = 0; k < 4; ++k) {
        int idx = base + k;
        if (idx < N_NODES) sum += cnt[idx];
    }
    s[t] = sum;
    __syncthreads();
    for (int off = 128; off > 0; off >>= 1) {
        if (t < off) s[t] += s[t + off];
        __syncthreads();
    }
    if (t == 0) bsum[b] = s[0];
}

__global__ __launch_bounds__(128) void scan2_kernel(
    const int* __restrict__ bsum, int* __restrict__ bofs, int* __restrict__ row_ptr)
{
    __shared__ int s[128];
    const int t = (int)threadIdx.x;
    const int v = (t < NB_SCAN) ? bsum[t] : 0;
    s[t] = v;
    __syncthreads();
    for (int off = 1; off < 128; off <<= 1) {
        int add = (t >= off) ? s[t - off] : 0;
        __syncthreads();
        s[t] += add;
        __syncthreads();
    }
    if (t < NB_SCAN) bofs[t] = s[t] - v;
    if (t == NB_SCAN - 1) row_ptr[N_NODES] = s[t];
}

__global__ __launch_bounds__(256) void scan3_kernel(
    const int* __restrict__ cnt, const int* __restrict__ bofs,
    int* __restrict__ row_ptr, int* __restrict__ pos)
{
    __shared__ int s[256];
    const int b = (int)blockIdx.x, t = (int)threadIdx.x;
    const int base = b * SCAN_CHUNK + t * 4;
    int v[4];
    int sum = 0;
#pragma unroll
    for (int k = 0; k < 4; ++k) {
        int idx = base + k;
        v[k] = (idx < N_NODES) ? cnt[idx] : 0;
        sum += v[k];
    }
    s[t] = sum;
    __syncthreads();
    for (int off = 1; off < 256; off <<= 1) {
        int add = (t >= off) ? s[t - off] : 0;
        __syncthreads();
        s[t] += add;
        __syncthreads();
    }
    int run = s[t] - sum + bofs[b];
#pragma unroll
    for (int k = 0; k < 4; ++k) {
        int idx = base + k;
        if (idx < N_NODES) {
            row_ptr[idx] = run;
            pos[idx] = run;
            run += v[k];
        }
    }
}

__global__ __launch_bounds__(256) void scatter_kernel(
    const int* __restrict__ src, const int* __restrict__ dst,
    int* __restrict__ pos, int* __restrict__ perm_e, int* __restrict__ perm_src)
{
    int i = (int)(blockIdx.x * blockDim.x + threadIdx.x);
    const int stride = (int)(gridDim.x * blockDim.x);
    for (; i < N_EDGES; i += stride) {
        const int d = dst[i];
        const int p = atomicAdd(&pos[d], 1);
        perm_e[p] = i;
        perm_src[p] = src[i];
    }
}

// ---------------------------------------------------------------------------
// Pre-permute edge_attr into dst-sorted order (one float4 per thread-iter;
// writes fully coalesced & contiguous).  One-time cost shared by 3 layers.
// ---------------------------------------------------------------------------
__global__ __launch_bounds__(256) void permute_attr_kernel(
    const float* __restrict__ eattr, const int* __restrict__ perm_e,
    float* __restrict__ attr_s)
{
    const int total = N_EDGES * (EDIM / 4);
    int i = (int)(blockIdx.x * blockDim.x + threadIdx.x);
    const int stride = (int)(gridDim.x * blockDim.x);
    for (; i < total; i += stride) {
        const int p = i >> 3, jj = i & 7;
        const int e = perm_e[p];
        ((float4*)attr_s)[i] = ((const float4*)eattr)[(size_t)e * 8 + jj];
    }
}

// ---------------------------------------------------------------------------
// Segmented edge-message sum, sorted attr: one wave per dst node, lane =
// feature.  4-edge unroll: 4 independent x-gathers + 32 linear-address attr
// loads in flight before the FMA chain consumes them.
// ---------------------------------------------------------------------------
__global__ __launch_bounds__(256) void gather_sorted_kernel(
    const float* __restrict__ x, const float* __restrict__ attr,
    const int* __restrict__ row_ptr, const int* __restrict__ perm_src,
    const float* __restrict__ We, const float* __restrict__ be,
    float* __restrict__ agg)
{
    const int lane = threadIdx.x & 63;
    const int wid  = (int)((blockIdx.x * blockDim.x + threadIdx.x) >> 6);
    if (wid >= N_NODES) return;

    float w[EDIM];
#pragma unroll
    for (int k = 0; k < EDIM; ++k) w[k] = We[k * HID + lane];
    const float bias = be[lane];

    const int begin = row_ptr[wid];
    const int end   = row_ptr[wid + 1];

    float sum = 0.0f;
    int j = begin;
    for (; j + 4 <= end; j += 4) {
        const int s0 = perm_src[j + 0];
        const int s1 = perm_src[j + 1];
        const int s2 = perm_src[j + 2];
        const int s3 = perm_src[j + 3];
        const float4* p = (const float4*)(attr + (size_t)j * EDIM);

        const float x0 = x[(size_t)s0 * HID + lane];
        const float x1 = x[(size_t)s1 * HID + lane];
        const float x2 = x[(size_t)s2 * HID + lane];
        const float x3 = x[(size_t)s3 * HID + lane];

        float a0 = bias, a1 = bias, a2 = bias, a3 = bias;
#pragma unroll
        for (int jj = 0; jj < 8; ++jj) {
            const float4 q0 = p[jj];
            const float4 q1 = p[8 + jj];
            const float4 q2 = p[16 + jj];
            const float4 q3 = p[24 + jj];
            a0 = fmaf(q0.x, w[4 * jj + 0], a0); a0 = fmaf(q0.y, w[4 * jj + 1], a0);
            a0 = fmaf(q0.z, w[4 * jj + 2], a0); a0 = fmaf(q0.w, w[4 * jj + 3], a0);
            a1 = fmaf(q1.x, w[4 * jj + 0], a1); a1 = fmaf(q1.y, w[4 * jj + 1], a1);
            a1 = fmaf(q1.z, w[4 * jj + 2], a1); a1 = fmaf(q1.w, w[4 * jj + 3], a1);
            a2 = fmaf(q2.x, w[4 * jj + 0], a2); a2 = fmaf(q2.y, w[4 * jj + 1], a2);
            a2 = fmaf(q2.z, w[4 * jj + 2], a2); a2 = fmaf(q2.w, w[4 * jj + 3], a2);
            a3 = fmaf(q3.x, w[4 * jj + 0], a3); a3 = fmaf(q3.y, w[4 * jj + 1], a3);
            a3 = fmaf(q3.z, w[4 * jj + 2], a3); a3 = fmaf(q3.w, w[4 * jj + 3], a3);
        }
        sum += fmaxf(x0 + a0, 0.0f) + fmaxf(x1 + a1, 0.0f)
             + fmaxf(x2 + a2, 0.0f) + fmaxf(x3 + a3, 0.0f);
    }
    for (; j < end; ++j) {
        const int s = perm_src[j];
        const float4* p = (const float4*)(attr + (size_t)j * EDIM);
        float acc = bias;
#pragma unroll
        for (int jj = 0; jj < 8; ++jj) {
            const float4 q = p[jj];
            acc = fmaf(q.x, w[4 * jj + 0], acc); acc = fmaf(q.y, w[4 * jj + 1], acc);
            acc = fmaf(q.z, w[4 * jj + 2], acc); acc = fmaf(q.w, w[4 * jj + 3], acc);
        }
        sum += fmaxf(x[(size_t)s * HID + lane] + acc, 0.0f);
    }
    agg[(size_t)wid * HID + lane] = sum;
}

// ---------------------------------------------------------------------------
// Fallback (workspace too small for sorted attr): same 4-edge unroll but
// attr rows fetched through perm_e.
// ---------------------------------------------------------------------------
__global__ __launch_bounds__(256) void gather_indexed_kernel(
    const float* __restrict__ x, const float* __restrict__ eattr,
    const int* __restrict__ row_ptr, const int* __restrict__ perm_e,
    const int* __restrict__ perm_src,
    const float* __restrict__ We, const float* __restrict__ be,
    float* __restrict__ agg)
{
    const int lane = threadIdx.x & 63;
    const int wid  = (int)((blockIdx.x * blockDim.x + threadIdx.x) >> 6);
    if (wid >= N_NODES) return;

    float w[EDIM];
#pragma unroll
    for (int k = 0; k < EDIM; ++k) w[k] = We[k * HID + lane];
    const float bias = be[lane];

    const int begin = row_ptr[wid];
    const int end   = row_ptr[wid + 1];

    float sum = 0.0f;
    int j = begin;
    for (; j + 4 <= end; j += 4) {
        const int e0 = perm_e[j + 0], e1 = perm_e[j + 1];
        const int e2 = perm_e[j + 2], e3 = perm_e[j + 3];
        const int s0 = perm_src[j + 0], s1 = perm_src[j + 1];
        const int s2 = perm_src[j + 2], s3 = perm_src[j + 3];
        const float4* p0 = (const float4*)(eattr + (size_t)e0 * EDIM);
        const float4* p1 = (const float4*)(eattr + (size_t)e1 * EDIM);
        const float4* p2 = (const float4*)(eattr + (size_t)e2 * EDIM);
        const float4* p3 = (const float4*)(eattr + (size_t)e3 * EDIM);

        const float x0 = x[(size_t)s0 * HID + lane];
        const float x1 = x[(size_t)s1 * HID + lane];
        const float x2 = x[(size_t)s2 * HID + lane];
        const float x3 = x[(size_t)s3 * HID + lane];

        float a0 = bias, a1 = bias, a2 = bias, a3 = bias;
#pragma unroll
        for (int jj = 0; jj < 8; ++jj) {
            const float4 q0 = p0[jj];
            const float4 q1 = p1[jj];
            const float4 q2 = p2[jj];
            const float4 q3 = p3[jj];
            a0 = fmaf(q0.x, w[4 * jj + 0], a0); a0 = fmaf(q0.y, w[4 * jj + 1], a0);
            a0 = fmaf(q0.z, w[4 * jj + 2], a0); a0 = fmaf(q0.w, w[4 * jj + 3], a0);
            a1 = fmaf(q1.x, w[4 * jj + 0], a1); a1 = fmaf(q1.y, w[4 * jj + 1], a1);
            a1 = fmaf(q1.z, w[4 * jj + 2], a1); a1 = fmaf(q1.w, w[4 * jj + 3], a1);
            a2 = fmaf(q2.x, w[4 * jj + 0], a2); a2 = fmaf(q2.y, w[4 * jj + 1], a2);
            a2 = fmaf(q2.z, w[4 * jj + 2], a2); a2 = fmaf(q2.w, w[4 * jj + 3], a2);
            a3 = fmaf(q3.x, w[4 * jj + 0], a3); a3 = fmaf(q3.y, w[4 * jj + 1], a3);
            a3 = fmaf(q3.z, w[4 * jj + 2], a3); a3 = fmaf(q3.w, w[4 * jj + 3], a3);
        }
        sum += fmaxf(x0 + a0, 0.0f) + fmaxf(x1 + a1, 0.0f)
             + fmaxf(x2 + a2, 0.0f) + fmaxf(x3 + a3, 0.0f);
    }
    for (; j < end; ++j) {
        const int e = perm_e[j];
        const int s = perm_src[j];
        const float4* p = (const float4*)(eattr + (size_t)e * EDIM);
        float acc = bias;
#pragma unroll
        for (int jj = 0; jj < 8; ++jj) {
            const float4 q = p[jj];
            acc = fmaf(q.x, w[4 * jj + 0], acc); acc = fmaf(q.y, w[4 * jj + 1], acc);
            acc = fmaf(q.z, w[4 * jj + 2], acc); acc = fmaf(q.w, w[4 * jj + 3], acc);
        }
        sum += fmaxf(x[(size_t)s * HID + lane] + acc, 0.0f);
    }
    agg[(size_t)wid * HID + lane] = sum;
}

// ---------------------------------------------------------------------------
// MLP kernel: lane = node.  u = relu((x+agg)@W1+b1)@W2+b2
// ---------------------------------------------------------------------------
__global__ __launch_bounds__(256) void mlp_kernel(
    const float* __restrict__ xin, const float* __restrict__ agg,
    const float* __restrict__ W1, const float* __restrict__ b1,
    const float* __restrict__ W2, const float* __restrict__ b2,
    float* __restrict__ uout)
{
    const int lane = threadIdx.x & 63;
    const int wid  = (int)((blockIdx.x * blockDim.x + threadIdx.x) >> 6);
    const int n    = wid * 64 + lane;
    const bool ok  = (n < N_NODES);
    const size_t base = (size_t)n * HID;

    float h[HID];
    if (ok) {
        const float4* px = (const float4*)(xin + base);
        const float4* pa = (const float4*)(agg + base);
#pragma unroll
        for (int j = 0; j < HID / 4; ++j) {
            float4 xv = px[j];
            float4 av = pa[j];
            h[4 * j + 0] = xv.x + av.x;
            h[4 * j + 1] = xv.y + av.y;
            h[4 * j + 2] = xv.z + av.z;
            h[4 * j + 3] = xv.w + av.w;
        }
    } else {
#pragma unroll
        for (int k = 0; k < HID; ++k) h[k] = 0.0f;
    }

    float u[HID];
#pragma unroll
    for (int f = 0; f < HID; ++f) u[f] = b2[f];

    for (int c = 0; c < 4; ++c) {
        float t[16];
#pragma unroll
        for (int j = 0; j < 16; ++j) t[j] = b1[c * 16 + j];
#pragma unroll
        for (int k = 0; k < HID; ++k) {
            const float hk = h[k];
#pragma unroll
            for (int j = 0; j < 16; ++j)
                t[j] = fmaf(hk, W1[k * HID + c * 16 + j], t[j]);
        }
#pragma unroll
        for (int j = 0; j < 16; ++j) t[j] = fmaxf(t[j], 0.0f);
#pragma unroll
        for (int j = 0; j < 16; ++j) {
            const float tj = t[j];
#pragma unroll
            for (int f = 0; f < HID; ++f)
                u[f] = fmaf(tj, W2[(c * 16 + j) * HID + f], u[f]);
        }
    }

    if (ok) {
        float4* po = (float4*)(uout + base);
#pragma unroll
        for (int j = 0; j < HID / 4; ++j)
            po[j] = make_float4(u[4 * j], u[4 * j + 1], u[4 * j + 2], u[4 * j + 3]);
    }
}

// ---------------------------------------------------------------------------
// Final projection: out = x @ Wout + bout
// ---------------------------------------------------------------------------
__global__ __launch_bounds__(256) void out_kernel(
    const float* __restrict__ xin, const float* __restrict__ Wo,
    const float* __restrict__ bo, float* __restrict__ out)
{
    const int lane = threadIdx.x & 63;
    const int wid  = (int)((blockIdx.x * blockDim.x + threadIdx.x) >> 6);
    const int n    = wid * 64 + lane;
    const bool ok  = (n < N_NODES);
    const size_t base = (size_t)n * HID;

    float h[HID];
    if (ok) {
        const float4* px = (const float4*)(xin + base);
#pragma unroll
        for (int j = 0; j < HID / 4; ++j) {
            float4 xv = px[j];
            h[4 * j + 0] = xv.x; h[4 * j + 1] = xv.y;
            h[4 * j + 2] = xv.z; h[4 * j + 3] = xv.w;
        }
    } else {
#pragma unroll
        for (int k = 0; k < HID; ++k) h[k] = 0.0f;
    }

    for (int c = 0; c < 4; ++c) {
        float t[16];
#pragma unroll
        for (int j = 0; j < 16; ++j) t[j] = bo[c * 16 + j];
#pragma unroll
        for (int k = 0; k < HID; ++k) {
            const float hk = h[k];
#pragma unroll
            for (int j = 0; j < 16; ++j)
                t[j] = fmaf(hk, Wo[k * HID + c * 16 + j], t[j]);
        }
        if (ok) {
            float4* po = (float4*)(out + base + c * 16);
#pragma unroll
            for (int j = 0; j < 4; ++j)
                po[j] = make_float4(t[4 * j], t[4 * j + 1], t[4 * j + 2], t[4 * j + 3]);
        }
    }
}

// ---------------------------------------------------------------------------
// BN statistics (sum / sumsq per feature)
// ---------------------------------------------------------------------------
__global__ __launch_bounds__(256) void stats_kernel(
    const float* __restrict__ u, float* __restrict__ stats)
{
    __shared__ float ls[256];
    __shared__ float ls2[256];
    const int tid = (int)threadIdx.x;
    const int g   = (int)(blockIdx.x * 256 + tid);
    const int f   = g & 63;
    const int row = g >> 6;
    const int rstride = (int)((gridDim.x * 256) >> 6);

    float s = 0.0f, s2 = 0.0f;
    for (int n = row; n < N_NODES; n += rstride) {
        float v = u[(size_t)n * HID + f];
        s += v;
        s2 = fmaf(v, v, s2);
    }
    ls[tid] = s;
    ls2[tid] = s2;
    __syncthreads();
    if (tid < 64) {
        float a = ls[tid] + ls[tid + 64] + ls[tid + 128] + ls[tid + 192];
        float b = ls2[tid] + ls2[tid + 64] + ls2[tid + 128] + ls2[tid + 192];
        atomicAdd(&stats[tid], a);
        atomicAdd(&stats[64 + tid], b);
    }
}

// ---------------------------------------------------------------------------
// BN apply + relu
// ---------------------------------------------------------------------------
__global__ __launch_bounds__(256) void bn_relu_kernel(
    const float* __restrict__ u, const float* __restrict__ stats,
    const float* __restrict__ gamma, const float* __restrict__ beta,
    float* __restrict__ xout)
{
    const int total4 = N_NODES * HID / 4;
    int i = (int)(blockIdx.x * blockDim.x + threadIdx.x);
    const int stride = (int)(gridDim.x * blockDim.x);
    const int fb = (i * 4) & 63;

    const float invN = 1.0f / (float)N_NODES;
    float sc[4], sh[4];
#pragma unroll
    for (int j = 0; j < 4; ++j) {
        float mean = stats[fb + j] * invN;
        float var  = stats[64 + fb + j] * invN - mean * mean;
        float s    = gamma[fb + j] * rsqrtf(var + BN_EPS);
        sc[j] = s;
        sh[j] = beta[fb + j] - mean * s;
    }
    for (; i < total4; i += stride) {
        float4 v = ((const float4*)u)[i];
        v.x = fmaxf(fmaf(v.x, sc[0], sh[0]), 0.0f);
        v.y = fmaxf(fmaf(v.y, sc[1], sh[1]), 0.0f);
        v.z = fmaxf(fmaf(v.z, sc[2], sh[2]), 0.0f);
        v.w = fmaxf(fmaf(v.w, sc[3], sh[3]), 0.0f);
        ((float4*)xout)[i] = v;
    }
}

// ---------------------------------------------------------------------------
extern "C" void kernel_launch(void* const* d_in, const int* in_sizes, int n_in,
                              void* d_out, int out_size, void* d_ws, size_t ws_size,
                              hipStream_t stream)
{
    const float* x0    = (const float*)d_in[0];
    const int*   eidx  = (const int*)d_in[1];
    const float* eattr = (const float*)d_in[2];
    const float* We    = (const float*)d_in[3];
    const float* be    = (const float*)d_in[4];
    const float* W1    = (const float*)d_in[5];
    const float* b1    = (const float*)d_in[6];
    const float* W2    = (const float*)d_in[7];
    const float* b2    = (const float*)d_in[8];
    const float* gamma = (const float*)d_in[9];
    const float* beta  = (const float*)d_in[10];
    const float* Wout  = (const float*)d_in[11];
    const float* bout  = (const float*)d_in[12];
    float* out = (float*)d_out;

    const int* src = eidx;
    const int* dst = eidx + N_EDGES;

    const size_t NH = (size_t)N_NODES * HID;

    // workspace layout (fp32/int32 elements)
    float* A     = (float*)d_ws;                 // post-layer x        (NH)
    float* AGG   = A + NH;                       // segmented sums      (NH)
    float* stats = AGG + NH;                     // 128 floats
    int* cnt      = (int*)(stats + 128);         // N_NODES
    int* bsum     = cnt + N_NODES;               // NB_SCAN (pad 128)
    int* bofs     = bsum + 128;                  // NB_SCAN (pad 128)
    int* row_ptr  = bofs + 128;                  // N_NODES + 1
    int* pos      = row_ptr + N_NODES + 1;       // N_NODES
    int* perm_e   = pos + N_NODES;               // N_EDGES
    int* perm_src = perm_e + N_EDGES;            // N_EDGES
    float* attr_s = (float*)(perm_src + N_EDGES);// N_EDGES*EDIM (204.8 MB, optional)
    float* B = out;                              // pre-BN MLP output (reuse d_out)

    const size_t base_elems   = (size_t)(perm_src + N_EDGES - (int*)d_ws);
    const size_t need_sorted  = (base_elems + (size_t)N_EDGES * EDIM) * 4;
    const bool   use_sorted   = (ws_size >= need_sorted);

    // ---- build CSR-by-dst (once; shared by all 3 layers) ----
    hipMemsetAsync(cnt, 0, N_NODES * sizeof(int), stream);
    hist_kernel<<<1024, 256, 0, stream>>>(dst, cnt);
    scan1_kernel<<<NB_SCAN, 256, 0, stream>>>(cnt, bsum);
    scan2_kernel<<<1, 128, 0, stream>>>(bsum, bofs, row_ptr);
    scan3_kernel<<<NB_SCAN, 256, 0, stream>>>(cnt, bofs, row_ptr, pos);
    scatter_kernel<<<1024, 256, 0, stream>>>(src, dst, pos, perm_e, perm_src);
    if (use_sorted)
        permute_attr_kernel<<<2048, 256, 0, stream>>>(eattr, perm_e, attr_s);

    const int mlp_blocks    = ((N_NODES + 63) / 64 + 3) / 4;       // 391
    const int gather_blocks = (N_NODES + 3) / 4;                   // 25000

    const float* xin = x0;
    for (int i = 0; i < 3; ++i) {
        hipMemsetAsync(stats, 0, 128 * sizeof(float), stream);

        if (use_sorted)
            gather_sorted_kernel<<<gather_blocks, 256, 0, stream>>>(
                xin, attr_s, row_ptr, perm_src,
                We + (size_t)i * EDIM * HID, be + (size_t)i * HID, AGG);
        else
            gather_indexed_kernel<<<gather_blocks, 256, 0, stream>>>(
                xin, eattr, row_ptr, perm_e, perm_src,
                We + (size_t)i * EDIM * HID, be + (size_t)i * HID, AGG);

        mlp_kernel<<<mlp_blocks, 256, 0, stream>>>(
            xin, AGG,
            W1 + (size_t)i * HID * HID, b1 + (size_t)i * HID,
            W2 + (size_t)i * HID * HID, b2 + (size_t)i * HID, B);

        stats_kernel<<<256, 256, 0, stream>>>(B, stats);

        bn_relu_kernel<<<1024, 256, 0, stream>>>(
            B, stats, gamma + (size_t)i * HID, beta + (size_t)i * HID, A);

        xin = A;
    }

    out_kernel<<<mlp_blocks, 256, 0, stream>>>(A, Wout, bout, out);
}

// Round 4
// 1747.395 us; speedup vs baseline: 1.6457x; 1.6457x over previous
//
#include <hip/hip_runtime.h>

#define N_NODES 100000
#define N_EDGES 1600000
#define HID 64
#define EDIM 32
#define BN_EPS 1e-5f

#define SCAN_CHUNK 1024
#define NB_SCAN ((N_NODES + SCAN_CHUNK - 1) / SCAN_CHUNK)   // 98

#define G_NODES 16      // dst nodes per block (gather)
#define CAP 320         // edges staged in LDS per chunk (40 KB attr)

// ---------------------------------------------------------------------------
// Counting sort of edges by dst.  Built once per call, reused by all 3 layers.
// ---------------------------------------------------------------------------
__global__ __launch_bounds__(256) void hist_kernel(
    const int* __restrict__ dst, int* __restrict__ cnt)
{
    int i = (int)(blockIdx.x * blockDim.x + threadIdx.x);
    const int stride = (int)(gridDim.x * blockDim.x);
    for (; i < N_EDGES; i += stride) atomicAdd(&cnt[dst[i]], 1);
}

__global__ __launch_bounds__(256) void scan1_kernel(
    const int* __restrict__ cnt, int* __restrict__ bsum)
{
    __shared__ int s[256];
    const int b = (int)blockIdx.x, t = (int)threadIdx.x;
    const int base = b * SCAN_CHUNK + t * 4;
    int sum = 0;
#pragma unroll
    for (int k = 0; k < 4; ++k) {
        int idx = base + k;
        if (idx < N_NODES) sum += cnt[idx];
    }
    s[t] = sum;
    __syncthreads();
    for (int off = 128; off > 0; off >>= 1) {
        if (t < off) s[t] += s[t + off];
        __syncthreads();
    }
    if (t == 0) bsum[b] = s[0];
}

__global__ __launch_bounds__(128) void scan2_kernel(
    const int* __restrict__ bsum, int* __restrict__ bofs, int* __restrict__ row_ptr)
{
    __shared__ int s[128];
    const int t = (int)threadIdx.x;
    const int v = (t < NB_SCAN) ? bsum[t] : 0;
    s[t] = v;
    __syncthreads();
    for (int off = 1; off < 128; off <<= 1) {
        int add = (t >= off) ? s[t - off] : 0;
        __syncthreads();
        s[t] += add;
        __syncthreads();
    }
    if (t < NB_SCAN) bofs[t] = s[t] - v;
    if (t == NB_SCAN - 1) row_ptr[N_NODES] = s[t];
}

__global__ __launch_bounds__(256) void scan3_kernel(
    const int* __restrict__ cnt, const int* __restrict__ bofs,
    int* __restrict__ row_ptr, int* __restrict__ pos)
{
    __shared__ int s[256];
    const int b = (int)blockIdx.x, t = (int)threadIdx.x;
    const int base = b * SCAN_CHUNK + t * 4;
    int v[4];
    int sum = 0;
#pragma unroll
    for (int k = 0; k < 4; ++k) {
        int idx = base + k;
        v[k] = (idx < N_NODES) ? cnt[idx] : 0;
        sum += v[k];
    }
    s[t] = sum;
    __syncthreads();
    for (int off = 1; off < 256; off <<= 1) {
        int add = (t >= off) ? s[t - off] : 0;
        __syncthreads();
        s[t] += add;
        __syncthreads();
    }
    int run = s[t] - sum + bofs[b];
#pragma unroll
    for (int k = 0; k < 4; ++k) {
        int idx = base + k;
        if (idx < N_NODES) {
            row_ptr[idx] = run;
            pos[idx] = run;
            run += v[k];
        }
    }
}

__global__ __launch_bounds__(256) void scatter_kernel(
    const int* __restrict__ src, const int* __restrict__ dst,
    int* __restrict__ pos, int* __restrict__ perm_e, int* __restrict__ perm_src)
{
    int i = (int)(blockIdx.x * blockDim.x + threadIdx.x);
    const int stride = (int)(gridDim.x * blockDim.x);
    for (; i < N_EDGES; i += stride) {
        const int d = dst[i];
        const int p = atomicAdd(&pos[d], 1);
        perm_e[p] = i;
        perm_src[p] = src[i];
    }
}

// ---------------------------------------------------------------------------
// Gather, LDS-staged: block = 4 waves = 16 dst nodes = one contiguous sorted
// edge range.  Chunked: stage <=CAP edges' attr (coalesced float4, via
// perm_e) + src into LDS, then each wave serially accumulates its 4 nodes
// with broadcast ds_read_b128 attr + 32 FMA + pipelined x-gather.  No atomics.
// ---------------------------------------------------------------------------
__global__ __launch_bounds__(256) void gather_staged_kernel(
    const float* __restrict__ x, const float* __restrict__ eattr,
    const int* __restrict__ row_ptr, const int* __restrict__ perm_e,
    const int* __restrict__ perm_src,
    const float* __restrict__ We, const float* __restrict__ be,
    float* __restrict__ agg)
{
    __shared__ float s_attr[CAP * EDIM];   // 40 KB
    __shared__ int   s_src[CAP];           // 1.25 KB

    const int tid  = (int)threadIdx.x;
    const int lane = tid & 63;
    const int w    = tid >> 6;                    // wave 0..3
    const int node_lo = (int)blockIdx.x * G_NODES;

    // this lane's weight column (reused for all ~256 edges of the block)
    float wv[EDIM];
#pragma unroll
    for (int k = 0; k < EDIM; ++k) wv[k] = We[k * HID + lane];
    const float bias = be[lane];

    // this wave's 4 node ranges
    int rp[5];
#pragma unroll
    for (int i = 0; i < 5; ++i) {
        int n = node_lo + 4 * w + i;
        rp[i] = row_ptr[n < N_NODES ? n : N_NODES];
    }
    float acc[4] = {0.0f, 0.0f, 0.0f, 0.0f};

    const int e0 = row_ptr[node_lo < N_NODES ? node_lo : N_NODES];
    const int hi = node_lo + G_NODES;
    const int e1 = row_ptr[hi < N_NODES ? hi : N_NODES];

    for (int c0 = e0; c0 < e1; c0 += CAP) {
        const int cnt = (e1 - c0 < CAP) ? (e1 - c0) : CAP;
        __syncthreads();                           // LDS safe to overwrite
        // stage attr rows (perm_e-indexed; 8 lanes per row, 128 B coalesced)
        for (int i = tid; i < cnt * 8; i += 256) {
            const int row = i >> 3, part = i & 7;
            const int ep = perm_e[c0 + row];
            ((float4*)s_attr)[i] = ((const float4*)eattr)[(size_t)ep * 8 + part];
        }
        for (int i = tid; i < cnt; i += 256) s_src[i] = perm_src[c0 + i];
        __syncthreads();
        const int c1 = c0 + cnt;

#pragma unroll
        for (int q = 0; q < 4; ++q) {
            const int jb = (rp[q]     > c0) ? rp[q]     : c0;
            const int je = (rp[q + 1] < c1) ? rp[q + 1] : c1;
            float a = acc[q];
            int j = jb;
            if (j < je) {
                // software pipeline: x-gather one edge ahead of its use
                int s0 = s_src[j - c0];
                float xv = x[(size_t)s0 * HID + lane];
                while (j < je) {
                    const float4* p = (const float4*)(s_attr + (size_t)(j - c0) * EDIM);
                    const int jn = j + 1;
                    float xn = 0.0f;
                    if (jn < je) {
                        const int sn = s_src[jn - c0];
                        xn = x[(size_t)sn * HID + lane];
                    }
                    float e = bias;
#pragma unroll
                    for (int jj = 0; jj < 8; ++jj) {
                        const float4 qv = p[jj];
                        e = fmaf(qv.x, wv[4 * jj + 0], e);
                        e = fmaf(qv.y, wv[4 * jj + 1], e);
                        e = fmaf(qv.z, wv[4 * jj + 2], e);
                        e = fmaf(qv.w, wv[4 * jj + 3], e);
                    }
                    a += fmaxf(xv + e, 0.0f);
                    xv = xn;
                    j = jn;
                }
            }
            acc[q] = a;
        }
    }

#pragma unroll
    for (int q = 0; q < 4; ++q) {
        const int n = node_lo + 4 * w + q;
        if (n < N_NODES) agg[(size_t)n * HID + lane] = acc[q];
    }
}

// ---------------------------------------------------------------------------
// MLP kernel: lane = node.  u = relu((x+agg)@W1+b1)@W2+b2
// ---------------------------------------------------------------------------
__global__ __launch_bounds__(256) void mlp_kernel(
    const float* __restrict__ xin, const float* __restrict__ agg,
    const float* __restrict__ W1, const float* __restrict__ b1,
    const float* __restrict__ W2, const float* __restrict__ b2,
    float* __restrict__ uout)
{
    const int lane = threadIdx.x & 63;
    const int wid  = (int)((blockIdx.x * blockDim.x + threadIdx.x) >> 6);
    const int n    = wid * 64 + lane;
    const bool ok  = (n < N_NODES);
    const size_t base = (size_t)n * HID;

    float h[HID];
    if (ok) {
        const float4* px = (const float4*)(xin + base);
        const float4* pa = (const float4*)(agg + base);
#pragma unroll
        for (int j = 0; j < HID / 4; ++j) {
            float4 xv = px[j];
            float4 av = pa[j];
            h[4 * j + 0] = xv.x + av.x;
            h[4 * j + 1] = xv.y + av.y;
            h[4 * j + 2] = xv.z + av.z;
            h[4 * j + 3] = xv.w + av.w;
        }
    } else {
#pragma unroll
        for (int k = 0; k < HID; ++k) h[k] = 0.0f;
    }

    float u[HID];
#pragma unroll
    for (int f = 0; f < HID; ++f) u[f] = b2[f];

    for (int c = 0; c < 4; ++c) {
        float t[16];
#pragma unroll
        for (int j = 0; j < 16; ++j) t[j] = b1[c * 16 + j];
#pragma unroll
        for (int k = 0; k < HID; ++k) {
            const float hk = h[k];
#pragma unroll
            for (int j = 0; j < 16; ++j)
                t[j] = fmaf(hk, W1[k * HID + c * 16 + j], t[j]);
        }
#pragma unroll
        for (int j = 0; j < 16; ++j) t[j] = fmaxf(t[j], 0.0f);
#pragma unroll
        for (int j = 0; j < 16; ++j) {
            const float tj = t[j];
#pragma unroll
            for (int f = 0; f < HID; ++f)
                u[f] = fmaf(tj, W2[(c * 16 + j) * HID + f], u[f]);
        }
    }

    if (ok) {
        float4* po = (float4*)(uout + base);
#pragma unroll
        for (int j = 0; j < HID / 4; ++j)
            po[j] = make_float4(u[4 * j], u[4 * j + 1], u[4 * j + 2], u[4 * j + 3]);
    }
}

// ---------------------------------------------------------------------------
// Final projection: out = x @ Wout + bout
// ---------------------------------------------------------------------------
__global__ __launch_bounds__(256) void out_kernel(
    const float* __restrict__ xin, const float* __restrict__ Wo,
    const float* __restrict__ bo, float* __restrict__ out)
{
    const int lane = threadIdx.x & 63;
    const int wid  = (int)((blockIdx.x * blockDim.x + threadIdx.x) >> 6);
    const int n    = wid * 64 + lane;
    const bool ok  = (n < N_NODES);
    const size_t base = (size_t)n * HID;

    float h[HID];
    if (ok) {
        const float4* px = (const float4*)(xin + base);
#pragma unroll
        for (int j = 0; j < HID / 4; ++j) {
            float4 xv = px[j];
            h[4 * j + 0] = xv.x; h[4 * j + 1] = xv.y;
            h[4 * j + 2] = xv.z; h[4 * j + 3] = xv.w;
        }
    } else {
#pragma unroll
        for (int k = 0; k < HID; ++k) h[k] = 0.0f;
    }

    for (int c = 0; c < 4; ++c) {
        float t[16];
#pragma unroll
        for (int j = 0; j < 16; ++j) t[j] = bo[c * 16 + j];
#pragma unroll
        for (int k = 0; k < HID; ++k) {
            const float hk = h[k];
#pragma unroll
            for (int j = 0; j < 16; ++j)
                t[j] = fmaf(hk, Wo[k * HID + c * 16 + j], t[j]);
        }
        if (ok) {
            float4* po = (float4*)(out + base + c * 16);
#pragma unroll
            for (int j = 0; j < 4; ++j)
                po[j] = make_float4(t[4 * j], t[4 * j + 1], t[4 * j + 2], t[4 * j + 3]);
        }
    }
}

// ---------------------------------------------------------------------------
// BN statistics (sum / sumsq per feature)
// ---------------------------------------------------------------------------
__global__ __launch_bounds__(256) void stats_kernel(
    const float* __restrict__ u, float* __restrict__ stats)
{
    __shared__ float ls[256];
    __shared__ float ls2[256];
    const int tid = (int)threadIdx.x;
    const int g   = (int)(blockIdx.x * 256 + tid);
    const int f   = g & 63;
    const int row = g >> 6;
    const int rstride = (int)((gridDim.x * 256) >> 6);

    float s = 0.0f, s2 = 0.0f;
    for (int n = row; n < N_NODES; n += rstride) {
        float v = u[(size_t)n * HID + f];
        s += v;
        s2 = fmaf(v, v, s2);
    }
    ls[tid] = s;
    ls2[tid] = s2;
    __syncthreads();
    if (tid < 64) {
        float a = ls[tid] + ls[tid + 64] + ls[tid + 128] + ls[tid + 192];
        float b = ls2[tid] + ls2[tid + 64] + ls2[tid + 128] + ls2[tid + 192];
        atomicAdd(&stats[tid], a);
        atomicAdd(&stats[64 + tid], b);
    }
}

// ---------------------------------------------------------------------------
// BN apply + relu
// ---------------------------------------------------------------------------
__global__ __launch_bounds__(256) void bn_relu_kernel(
    const float* __restrict__ u, const float* __restrict__ stats,
    const float* __restrict__ gamma, const float* __restrict__ beta,
    float* __restrict__ xout)
{
    const int total4 = N_NODES * HID / 4;
    int i = (int)(blockIdx.x * blockDim.x + threadIdx.x);
    const int stride = (int)(gridDim.x * blockDim.x);
    const int fb = (i * 4) & 63;

    const float invN = 1.0f / (float)N_NODES;
    float sc[4], sh[4];
#pragma unroll
    for (int j = 0; j < 4; ++j) {
        float mean = stats[fb + j] * invN;
        float var  = stats[64 + fb + j] * invN - mean * mean;
        float s    = gamma[fb + j] * rsqrtf(var + BN_EPS);
        sc[j] = s;
        sh[j] = beta[fb + j] - mean * s;
    }
    for (; i < total4; i += stride) {
        float4 v = ((const float4*)u)[i];
        v.x = fmaxf(fmaf(v.x, sc[0], sh[0]), 0.0f);
        v.y = fmaxf(fmaf(v.y, sc[1], sh[1]), 0.0f);
        v.z = fmaxf(fmaf(v.z, sc[2], sh[2]), 0.0f);
        v.w = fmaxf(fmaf(v.w, sc[3], sh[3]), 0.0f);
        ((float4*)xout)[i] = v;
    }
}

// ---------------------------------------------------------------------------
extern "C" void kernel_launch(void* const* d_in, const int* in_sizes, int n_in,
                              void* d_out, int out_size, void* d_ws, size_t ws_size,
                              hipStream_t stream)
{
    const float* x0    = (const float*)d_in[0];
    const int*   eidx  = (const int*)d_in[1];
    const float* eattr = (const float*)d_in[2];
    const float* We    = (const float*)d_in[3];
    const float* be    = (const float*)d_in[4];
    const float* W1    = (const float*)d_in[5];
    const float* b1    = (const float*)d_in[6];
    const float* W2    = (const float*)d_in[7];
    const float* b2    = (const float*)d_in[8];
    const float* gamma = (const float*)d_in[9];
    const float* beta  = (const float*)d_in[10];
    const float* Wout  = (const float*)d_in[11];
    const float* bout  = (const float*)d_in[12];
    float* out = (float*)d_out;

    const int* src = eidx;
    const int* dst = eidx + N_EDGES;

    const size_t NH = (size_t)N_NODES * HID;

    // workspace layout (fp32/int32 elements)
    float* A     = (float*)d_ws;                 // post-layer x        (NH)
    float* AGG   = A + NH;                       // segmented sums      (NH)
    float* stats = AGG + NH;                     // 128 floats
    int* cnt      = (int*)(stats + 128);         // N_NODES
    int* bsum     = cnt + N_NODES;               // NB_SCAN (pad 128)
    int* bofs     = bsum + 128;                  // NB_SCAN (pad 128)
    int* row_ptr  = bofs + 128;                  // N_NODES + 1
    int* pos      = row_ptr + N_NODES + 1;       // N_NODES
    int* perm_e   = pos + N_NODES;               // N_EDGES
    int* perm_src = perm_e + N_EDGES;            // N_EDGES
    float* B = out;                              // pre-BN MLP output (reuse d_out)

    // ---- build CSR-by-dst (once; shared by all 3 layers) ----
    hipMemsetAsync(cnt, 0, N_NODES * sizeof(int), stream);
    hist_kernel<<<1024, 256, 0, stream>>>(dst, cnt);
    scan1_kernel<<<NB_SCAN, 256, 0, stream>>>(cnt, bsum);
    scan2_kernel<<<1, 128, 0, stream>>>(bsum, bofs, row_ptr);
    scan3_kernel<<<NB_SCAN, 256, 0, stream>>>(cnt, bofs, row_ptr, pos);
    scatter_kernel<<<1024, 256, 0, stream>>>(src, dst, pos, perm_e, perm_src);

    const int mlp_blocks    = ((N_NODES + 63) / 64 + 3) / 4;           // 391
    const int gather_blocks = (N_NODES + G_NODES - 1) / G_NODES;       // 6250

    const float* xin = x0;
    for (int i = 0; i < 3; ++i) {
        hipMemsetAsync(stats, 0, 128 * sizeof(float), stream);

        gather_staged_kernel<<<gather_blocks, 256, 0, stream>>>(
            xin, eattr, row_ptr, perm_e, perm_src,
            We + (size_t)i * EDIM * HID, be + (size_t)i * HID, AGG);

        mlp_kernel<<<mlp_blocks, 256, 0, stream>>>(
            xin, AGG,
            W1 + (size_t)i * HID * HID, b1 + (size_t)i * HID,
            W2 + (size_t)i * HID * HID, b2 + (size_t)i * HID, B);

        stats_kernel<<<256, 256, 0, stream>>>(B, stats);

        bn_relu_kernel<<<1024, 256, 0, stream>>>(
            B, stats, gamma + (size_t)i * HID, beta + (size_t)i * HID, A);

        xin = A;
    }

    out_kernel<<<mlp_blocks, 256, 0, stream>>>(A, Wout, bout, out);
}